// Round 7
// baseline (80.860 us; speedup 1.0000x reference)
//
#include <hip/hip_runtime.h>
#include <hip/hip_bf16.h>
#include <stdint.h>

typedef short bh8 __attribute__((ext_vector_type(8)));
typedef short bh4 __attribute__((ext_vector_type(4)));
typedef float fx4 __attribute__((ext_vector_type(4)));

#define B_ 8
#define S_ 2048
#define E_ 1024
#define HD_ 64

__device__ __forceinline__ short f2bf(float f) {
  unsigned u = __builtin_bit_cast(unsigned, f);
  u = u + 0x7FFFu + ((u >> 16) & 1u);   // RNE
  return (short)(u >> 16);
}
__device__ __forceinline__ float bf2f(short s) {
  unsigned u = ((unsigned)(unsigned short)s) << 16;
  return __builtin_bit_cast(float, u);
}

#define GL2LDS16(gp, lp) __builtin_amdgcn_global_load_lds( \
    (const __attribute__((address_space(1))) unsigned int*)(gp), \
    (__attribute__((address_space(3))) unsigned int*)(lp), 16, 0, 0)

// ---------- cast W (3 x [64][1024] f32) -> wc bf16 [192][1024], order K,Q,V ----------
__global__ __launch_bounds__(256) void castw_k(
    const float* __restrict__ wk, const float* __restrict__ wq,
    const float* __restrict__ wv, short* __restrict__ wc) {
  int i = blockIdx.x * 256 + threadIdx.x;
  int wsel = i >> 13;
  int o = (i & 8191) * 8;
  const float* src = (wsel == 0) ? wk : (wsel == 1) ? wq : wv;
  float4 a = *(const float4*)(src + o);
  float4 b = *(const float4*)(src + o + 4);
  bh8 r = { f2bf(a.x), f2bf(a.y), f2bf(a.z), f2bf(a.w),
            f2bf(b.x), f2bf(b.y), f2bf(b.z), f2bf(b.w) };
  *(bh8*)(wc + wsel * (HD_ * E_) + o) = r;
}

// ---------- QKV GEMM (r3 version: single LDS buffer, 14KB, high block-TLP) ----------
__global__ __launch_bounds__(256) void qkv_gemm(
    const float* __restrict__ x, const short* __restrict__ wc,
    short* __restrict__ ko, short* __restrict__ qo, short* __restrict__ vt) {
  __shared__ short As[32 * 32];
  __shared__ short Bs[192 * 32];
  const int tid = threadIdx.x;
  const int w = tid >> 6, l = tid & 63;
  const int c = l & 15, g = l >> 4;
  const int r0 = blockIdx.x * 32;
  const int srow = l >> 2;
  const int scol = (l & 3) * 8;
  const int ar = tid >> 3;
  const int ac = (tid & 7) * 4;

  fx4 acc[2][3];
#pragma unroll
  for (int rt = 0; rt < 2; ++rt)
#pragma unroll
    for (int cc = 0; cc < 3; ++cc) acc[rt][cc] = (fx4){0.f, 0.f, 0.f, 0.f};

  for (int k0 = 0; k0 < E_; k0 += 32) {
    float4 av = *(const float4*)(x + (size_t)(r0 + ar) * E_ + k0 + ac);
    __syncthreads();
#pragma unroll
    for (int p = 0; p < 3; ++p)
      GL2LDS16(wc + (size_t)(16 * (w + 4 * p) + srow) * E_ + k0 + scol,
               &Bs[(w + 4 * p) * 512]);
    bh4 aw = { f2bf(av.x), f2bf(av.y), f2bf(av.z), f2bf(av.w) };
    *(bh4*)&As[ar * 32 + ac] = aw;
    __syncthreads();

    bh8 af[2], bf[3];
    af[0] = *(const bh8*)&As[c * 32 + 8 * g];
    af[1] = *(const bh8*)&As[(16 + c) * 32 + 8 * g];
#pragma unroll
    for (int cc = 0; cc < 3; ++cc)
      bf[cc] = *(const bh8*)&Bs[(16 * (3 * w + cc) + c) * 32 + 8 * g];
#pragma unroll
    for (int rt = 0; rt < 2; ++rt)
#pragma unroll
      for (int cc = 0; cc < 3; ++cc)
        acc[rt][cc] = __builtin_amdgcn_mfma_f32_16x16x32_bf16(af[rt], bf[cc], acc[rt][cc], 0, 0, 0);
  }

#pragma unroll
  for (int rt = 0; rt < 2; ++rt) {
    const int rbase = r0 + 16 * rt + 4 * g;
#pragma unroll
    for (int cc = 0; cc < 3; ++cc) {
      const int ctg = 3 * w + cc;
      const int n = 16 * ctg + c;
      if (ctg < 4) {
#pragma unroll
        for (int j = 0; j < 4; ++j)
          ko[(size_t)(rbase + j) * HD_ + n] = f2bf(acc[rt][cc][j]);
      } else if (ctg < 8) {
#pragma unroll
        for (int j = 0; j < 4; ++j)
          qo[(size_t)(rbase + j) * HD_ + (n - 64)] = f2bf(acc[rt][cc][j] * 0.125f);
      } else {
        const int hd = n - 128;
        const int bb = rbase >> 11, ss = rbase & (S_ - 1);
        bh4 pk = { f2bf(acc[rt][cc][0]), f2bf(acc[rt][cc][1]),
                   f2bf(acc[rt][cc][2]), f2bf(acc[rt][cc][3]) };
        *(bh4*)&vt[((size_t)(bb * HD_ + hd)) * S_ + ss] = pk;
      }
    }
  }
}

// chunk-prefix function: waves before pair-index u (chunks of 8 k-tiles)
__device__ __forceinline__ int Fcum(int u) {
  int q = u >> 2, r = u & 3;
  return 2 * q * (q + 1) + r * (q + 1);
}

// ---------- dual-q split-KV flash: 1 wave per (q-pair 2u,2u+1, 8-k-tile chunk) ----------
// 4352 waves, each <=8 iterations; K/V loads shared by 32 q-rows; two independent
// softmax chains per iteration (ILP). Partial O in bf16, m/l in f32.
__global__ __launch_bounds__(256, 4) void attn_split2(
    const short* __restrict__ qb, const short* __restrict__ kb,
    const short* __restrict__ vt, short* __restrict__ pO,
    float* __restrict__ pm, float* __restrict__ pl) {
  const int tid = threadIdx.x;
  const int w = tid >> 6, l = tid & 63;
  const int c = l & 15, g = l >> 4;
  const int wi = blockIdx.x * 4 + w;          // 0..4351
  const int b = wi / 544;
  const int ci = wi - b * 544;
  // decode ci -> (u, ch): Fcum(u) <= ci < Fcum(u+1)
  int u = (int)sqrtf(8.0f * ci + 1.0f);
  if (u > 63) u = 63;
  while (u > 0 && Fcum(u) > ci) --u;
  while (u < 63 && Fcum(u + 1) <= ci) ++u;
  const int ch = ci - Fcum(u);
  const int qtA = 2 * u, qtB = 2 * u + 1;
  const int kt0 = ch * 8;
  const int kt1 = min(kt0 + 8, qtB + 1);

  const short* qpA = qb + ((size_t)(b * S_ + qtA * 16 + c)) * HD_ + 8 * g;
  const short* qpB = qb + ((size_t)(b * S_ + qtB * 16 + c)) * HD_ + 8 * g;
  bh8 qA0 = *(const bh8*)qpA;
  bh8 qA1 = *(const bh8*)(qpA + 32);
  bh8 qB0 = *(const bh8*)qpB;
  bh8 qB1 = *(const bh8*)(qpB + 32);

  fx4 oA[4], oB[4];
#pragma unroll
  for (int mm = 0; mm < 4; ++mm) { oA[mm] = (fx4){0,0,0,0}; oB[mm] = (fx4){0,0,0,0}; }
  float mA = -1e30f, lA = 0.f, mB = -1e30f, lB = 0.f;

  const short* kbase = kb + (size_t)b * S_ * HD_ + (size_t)c * HD_ + 8 * g;
  const short* vbase = vt + ((size_t)(b * HD_ + c)) * S_ + 4 * g;

  for (int kt = kt0; kt < kt1; ++kt) {
    const short* kp = kbase + (size_t)kt * (16 * HD_);
    bh8 kf0 = *(const bh8*)kp;
    bh8 kf1 = *(const bh8*)(kp + 32);
    const short* vp = vbase + kt * 16;
    bh4 vf0 = *(const bh4*)vp;
    bh4 vf1 = *(const bh4*)(vp + 16 * S_);
    bh4 vf2 = *(const bh4*)(vp + 32 * S_);
    bh4 vf3 = *(const bh4*)(vp + 48 * S_);

    const bool actA = (kt <= qtA);            // wave-uniform
    fx4 sB = {0.f, 0.f, 0.f, 0.f};
    sB = __builtin_amdgcn_mfma_f32_16x16x32_bf16(kf0, qB0, sB, 0, 0, 0);
    sB = __builtin_amdgcn_mfma_f32_16x16x32_bf16(kf1, qB1, sB, 0, 0, 0);
    fx4 sA = {0.f, 0.f, 0.f, 0.f};
    if (actA) {
      sA = __builtin_amdgcn_mfma_f32_16x16x32_bf16(kf0, qA0, sA, 0, 0, 0);
      sA = __builtin_amdgcn_mfma_f32_16x16x32_bf16(kf1, qA1, sA, 0, 0, 0);
      if (kt == qtA) {
#pragma unroll
        for (int j = 0; j < 4; ++j)
          if (4 * g + j > c) sA[j] = -1e30f;
      }
    }
    if (kt == qtB) {
#pragma unroll
      for (int j = 0; j < 4; ++j)
        if (4 * g + j > c) sB[j] = -1e30f;
    }

    // dual online softmax (independent chains -> ILP)
    float tB = fmaxf(fmaxf(sB[0], sB[1]), fmaxf(sB[2], sB[3]));
    tB = fmaxf(tB, __shfl_xor(tB, 16, 64));
    tB = fmaxf(tB, __shfl_xor(tB, 32, 64));
    const float mBn = fmaxf(mB, tB);
    const float scB = __expf(mB - mBn);
    float pB0 = __expf(sB[0] - mBn), pB1 = __expf(sB[1] - mBn);
    float pB2 = __expf(sB[2] - mBn), pB3 = __expf(sB[3] - mBn);
    float tsB = (pB0 + pB1) + (pB2 + pB3);
    tsB += __shfl_xor(tsB, 16, 64);
    tsB += __shfl_xor(tsB, 32, 64);
    lB = lB * scB + tsB;
    mB = mBn;
#pragma unroll
    for (int mm = 0; mm < 4; ++mm) oB[mm] *= scB;
    bh4 pfB = { f2bf(pB0), f2bf(pB1), f2bf(pB2), f2bf(pB3) };
    oB[0] = __builtin_amdgcn_mfma_f32_16x16x16bf16_1k(vf0, pfB, oB[0], 0, 0, 0);
    oB[1] = __builtin_amdgcn_mfma_f32_16x16x16bf16_1k(vf1, pfB, oB[1], 0, 0, 0);
    oB[2] = __builtin_amdgcn_mfma_f32_16x16x16bf16_1k(vf2, pfB, oB[2], 0, 0, 0);
    oB[3] = __builtin_amdgcn_mfma_f32_16x16x16bf16_1k(vf3, pfB, oB[3], 0, 0, 0);

    if (actA) {
      float tA = fmaxf(fmaxf(sA[0], sA[1]), fmaxf(sA[2], sA[3]));
      tA = fmaxf(tA, __shfl_xor(tA, 16, 64));
      tA = fmaxf(tA, __shfl_xor(tA, 32, 64));
      const float mAn = fmaxf(mA, tA);
      const float scA = __expf(mA - mAn);
      float pA0 = __expf(sA[0] - mAn), pA1 = __expf(sA[1] - mAn);
      float pA2 = __expf(sA[2] - mAn), pA3 = __expf(sA[3] - mAn);
      float tsA = (pA0 + pA1) + (pA2 + pA3);
      tsA += __shfl_xor(tsA, 16, 64);
      tsA += __shfl_xor(tsA, 32, 64);
      lA = lA * scA + tsA;
      mA = mAn;
#pragma unroll
      for (int mm = 0; mm < 4; ++mm) oA[mm] *= scA;
      bh4 pfA = { f2bf(pA0), f2bf(pA1), f2bf(pA2), f2bf(pA3) };
      oA[0] = __builtin_amdgcn_mfma_f32_16x16x16bf16_1k(vf0, pfA, oA[0], 0, 0, 0);
      oA[1] = __builtin_amdgcn_mfma_f32_16x16x16bf16_1k(vf1, pfA, oA[1], 0, 0, 0);
      oA[2] = __builtin_amdgcn_mfma_f32_16x16x16bf16_1k(vf2, pfA, oA[2], 0, 0, 0);
      oA[3] = __builtin_amdgcn_mfma_f32_16x16x16bf16_1k(vf3, pfA, oA[3], 0, 0, 0);
    }
  }

  // partial O (bf16): [wi][qsel][row=c 16][col 64]; o[mm][j] = O[q=c][hd=16mm+4g+j]
#pragma unroll
  for (int mm = 0; mm < 4; ++mm) {
    bh4 a = { f2bf(oA[mm][0]), f2bf(oA[mm][1]), f2bf(oA[mm][2]), f2bf(oA[mm][3]) };
    bh4 bb = { f2bf(oB[mm][0]), f2bf(oB[mm][1]), f2bf(oB[mm][2]), f2bf(oB[mm][3]) };
    *(bh4*)(pO + ((size_t)wi * 2 + 0) * 1024 + c * 64 + 16 * mm + 4 * g) = a;
    *(bh4*)(pO + ((size_t)wi * 2 + 1) * 1024 + c * 64 + 16 * mm + 4 * g) = bb;
  }
  if (g == 0) {
    pm[wi * 32 + c] = mA;       pl[wi * 32 + c] = lA;
    pm[wi * 32 + 16 + c] = mB;  pl[wi * 32 + 16 + c] = lB;
  }
}

// ---------- combine partials: 1 wave per q-tile (1024 waves) ----------
__global__ __launch_bounds__(256) void attn_combine2(
    const short* __restrict__ pO, const float* __restrict__ pm,
    const float* __restrict__ pl, float* __restrict__ out) {
  const int tid = threadIdx.x;
  const int w = tid >> 6, l = tid & 63;
  const int qi = blockIdx.x * 4 + w;          // 0..1023
  const int b = qi >> 7, qt = qi & 127;
  const int u = qt >> 1, x = qt & 1;
  const int CH = (2 * u + 9) >> 3;            // ceil((2u+2)/8)
  const int base = b * 544 + Fcum(u);
  const int r = l >> 2, cg = l & 3;

  float M = -1e30f;
  for (int i = 0; i < CH; ++i)
    M = fmaxf(M, pm[(base + i) * 32 + x * 16 + r]);
  float L = 0.f;
  float acc[16];
#pragma unroll
  for (int j = 0; j < 16; ++j) acc[j] = 0.f;
  for (int i = 0; i < CH; ++i) {
    const float mi = pm[(base + i) * 32 + x * 16 + r];
    const float sc = __expf(mi - M);
    L += pl[(base + i) * 32 + x * 16 + r] * sc;
    const short* po = pO + ((size_t)(base + i) * 2 + x) * 1024 + r * 64 + cg * 16;
    bh8 v0 = *(const bh8*)po;
    bh8 v1 = *(const bh8*)(po + 8);
#pragma unroll
    for (int j = 0; j < 8; ++j) {
      acc[j] += sc * bf2f(v0[j]);
      acc[8 + j] += sc * bf2f(v1[j]);
    }
  }
  const float inv = 1.0f / L;
  float* op = out + ((size_t)(b * S_ + qt * 16 + r)) * HD_ + cg * 16;
#pragma unroll
  for (int j = 0; j < 16; ++j) op[j] = acc[j] * inv;
}

// ---------- fallback: 1-wave-per-q-tile attention (ws too small) ----------
__global__ __launch_bounds__(256) void attn_k(
    const short* __restrict__ qb, const short* __restrict__ kb,
    const short* __restrict__ vt, float* __restrict__ out) {
  const int tid = threadIdx.x;
  const int w = tid >> 6, l = tid & 63;
  const int c = l & 15, g = l >> 4;
  const int blk = blockIdx.x;
  const int b = blk >> 5, p = blk & 31;
  const int qt = (w == 0) ? 2 * p : (w == 1) ? 2 * p + 1
               : (w == 2) ? 126 - 2 * p : 127 - 2 * p;
  const int q0 = qt * 16;
  const short* qp = qb + ((size_t)(b * S_ + q0 + c)) * HD_ + 8 * g;
  bh8 qf0 = *(const bh8*)qp;
  bh8 qf1 = *(const bh8*)(qp + 32);
  fx4 o[4];
  o[0] = o[1] = o[2] = o[3] = (fx4){0.f, 0.f, 0.f, 0.f};
  float m = -1e30f, lsum = 0.f;
  for (int kt = 0; kt <= qt; ++kt) {
    const short* kp = kb + ((size_t)(b * S_ + kt * 16 + c)) * HD_ + 8 * g;
    bh8 kf0 = *(const bh8*)kp;
    bh8 kf1 = *(const bh8*)(kp + 32);
    fx4 s = {0.f, 0.f, 0.f, 0.f};
    s = __builtin_amdgcn_mfma_f32_16x16x32_bf16(kf0, qf0, s, 0, 0, 0);
    s = __builtin_amdgcn_mfma_f32_16x16x32_bf16(kf1, qf1, s, 0, 0, 0);
    if (kt == qt) {
#pragma unroll
      for (int j = 0; j < 4; ++j)
        if (4 * g + j > c) s[j] = -1e30f;
    }
    float tmax = fmaxf(fmaxf(s[0], s[1]), fmaxf(s[2], s[3]));
    tmax = fmaxf(tmax, __shfl_xor(tmax, 16, 64));
    tmax = fmaxf(tmax, __shfl_xor(tmax, 32, 64));
    const float mnew = fmaxf(m, tmax);
    const float scale = __expf(m - mnew);
    const float p0 = __expf(s[0] - mnew);
    const float p1 = __expf(s[1] - mnew);
    const float p2 = __expf(s[2] - mnew);
    const float p3 = __expf(s[3] - mnew);
    float ts = (p0 + p1) + (p2 + p3);
    ts += __shfl_xor(ts, 16, 64);
    ts += __shfl_xor(ts, 32, 64);
    lsum = lsum * scale + ts;
    m = mnew;
#pragma unroll
    for (int mm = 0; mm < 4; ++mm) o[mm] *= scale;
    bh4 pf = { f2bf(p0), f2bf(p1), f2bf(p2), f2bf(p3) };
    const short* vp = vt + (size_t)(b * HD_ + c) * S_ + kt * 16 + 4 * g;
#pragma unroll
    for (int mm = 0; mm < 4; ++mm) {
      bh4 vf = *(const bh4*)(vp + mm * 16 * S_);
      o[mm] = __builtin_amdgcn_mfma_f32_16x16x16bf16_1k(vf, pf, o[mm], 0, 0, 0);
    }
  }
  const float inv = 1.0f / lsum;
  float* op = out + ((size_t)(b * S_ + q0 + c)) * HD_ + 4 * g;
#pragma unroll
  for (int mm = 0; mm < 4; ++mm) {
    fx4 r = o[mm] * inv;
    *(fx4*)(op + 16 * mm) = r;
  }
}

extern "C" void kernel_launch(void* const* d_in, const int* in_sizes, int n_in,
                              void* d_out, int out_size, void* d_ws, size_t ws_size,
                              hipStream_t stream) {
  const float* x  = (const float*)d_in[0];
  const float* wk = (const float*)d_in[1];
  const float* wq = (const float*)d_in[2];
  const float* wv = (const float*)d_in[3];
  float* out = (float*)d_out;
  char* ws = (char*)d_ws;
  short* wc = (short*)(ws);                          // 384 KB
  short* kb = (short*)(ws + 393216);                 // 2 MB
  short* qb = (short*)(ws + 2490368);                // 2 MB
  short* vt = (short*)(ws + 4587520);                // 2 MB
  short* pO = (short*)(ws + 6684672);                // 4352*2048*2B = 17.8 MB
  float* pm = (float*)(ws + 24510464);               // 4352*32*4B = 557 KB
  float* pl = (float*)(ws + 25067520);               // 557 KB
  const size_t need = 25624576;

  castw_k<<<dim3(96), dim3(256), 0, stream>>>(wk, wq, wv, wc);
  qkv_gemm<<<dim3(512), dim3(256), 0, stream>>>(x, wc, kb, qb, vt);
  if (ws_size >= need) {
    attn_split2<<<dim3(1088), dim3(256), 0, stream>>>(qb, kb, vt, pO, pm, pl);
    attn_combine2<<<dim3(256), dim3(256), 0, stream>>>(pO, pm, pl, out);
  } else {
    attn_k<<<dim3(256), dim3(256), 0, stream>>>(qb, kb, vt, out);
  }
}